// Round 1
// baseline (42.785 us; speedup 1.0000x reference)
//
#include <hip/hip_runtime.h>
#include <math.h>

// Problem constants (from reference)
#define BATCH 128
#define NPRED 1024
#define NT 64
#define PD 85          // 5 + NUM_CLASSES
#define NLOGIT 79      // pred[:, 6:] -> 85 - 6 columns (reference quirk)

__device__ __forceinline__ float softplusf(float x) {
    // stable log(1 + exp(x)) == jax.nn.softplus
    return fmaxf(x, 0.0f) + log1pf(expf(-fabsf(x)));
}

// Block-wide sum over 1024 threads (16 waves). Result valid on tid==0 only.
// Deterministic: fixed shuffle order + fixed 16-element loop.
__device__ __forceinline__ float block_sum(float v, float* red) {
    const int tid = threadIdx.x;
    #pragma unroll
    for (int o = 32; o > 0; o >>= 1) v += __shfl_down(v, o);
    __syncthreads();                      // protect red[] reuse
    if ((tid & 63) == 0) red[tid >> 6] = v;
    __syncthreads();
    float r = 0.0f;
    if (tid == 0) {
        #pragma unroll
        for (int i = 0; i < 16; ++i) r += red[i];
    }
    return r;
}

__global__ __launch_bounds__(1024)
void detloss_kernel(const float* __restrict__ preds,
                    const float* __restrict__ targets,
                    float* __restrict__ per_sample) {
    const int b   = blockIdx.x;
    const int tid = threadIdx.x;

    __shared__ float tx1[NT], ty1[NT], tx2[NT], ty2[NT], tcls[NT], tarea[NT];
    __shared__ int   tvalid[NT];
    __shared__ float redf[16];
    __shared__ int   redi[16];
    __shared__ float gmax_s;
    __shared__ int   any_s;
    __shared__ int   kv_s;

    // --- stage targets into LDS ---
    if (tid < NT) {
        const float* tg = targets + ((size_t)b * NT + tid) * 5;
        float a = tg[0], c = tg[1], d = tg[2], e = tg[3], f = tg[4];
        tx1[tid] = a; ty1[tid] = c; tx2[tid] = d; ty2[tid] = e; tcls[tid] = f;
        tarea[tid] = (d - a) * (e - c);
        tvalid[tid] = (f >= 0.0f) ? 1 : 0;
    }
    __syncthreads();
    if (tid == 0) {
        int k = 0;
        #pragma unroll
        for (int t = 0; t < NT; ++t) k += tvalid[t];
        kv_s = k;
    }

    // --- per-thread prediction: best IoU / argmax over 64 targets ---
    const float* pp = preds + ((size_t)b * NPRED + tid) * PD;
    const float px1 = pp[0], py1 = pp[1], px2 = pp[2], py2 = pp[3], conf = pp[4];
    const float parea = (px2 - px1) * (py2 - py1);

    float best = -3.0e38f;
    int   bidx = 0;
    #pragma unroll 8
    for (int t = 0; t < NT; ++t) {
        float w = fminf(px2, tx2[t]) - fmaxf(px1, tx1[t]); w = fmaxf(w, 0.0f);
        float h = fminf(py2, ty2[t]) - fmaxf(py1, ty1[t]); h = fmaxf(h, 0.0f);
        float inter = w * h;
        float uni   = parea + tarea[t] - inter;
        float iou   = tvalid[t] ? inter / (uni + 1e-6f) : -1.0f;
        if (iou > best) { best = iou; bidx = t; }   // strict > => first-max (JAX argmax)
    }
    const bool mraw = best > 0.5f;

    // --- block reduce: global max of best_ious, any(matched_raw) ---
    {
        float v = best;
        #pragma unroll
        for (int o = 32; o > 0; o >>= 1) v = fmaxf(v, __shfl_down(v, o));
        unsigned long long bal = __ballot(mraw);
        if ((tid & 63) == 0) { redf[tid >> 6] = v; redi[tid >> 6] = (bal != 0ULL) ? 1 : 0; }
        __syncthreads();
        if (tid == 0) {
            float m = redf[0]; int a = redi[0];
            #pragma unroll
            for (int i = 1; i < 16; ++i) { m = fmaxf(m, redf[i]); a |= redi[i]; }
            gmax_s = m; any_s = a;
        }
        __syncthreads();
    }
    const float gmax = gmax_s;
    const bool  anym = (any_s != 0);
    const bool  matched = anym ? mraw : (best == gmax);  // exact-equality tie set, as in JAX
    const float m = matched ? 1.0f : 0.0f;

    // --- per-thread loss contributions ---
    const float sp_pos = softplusf(conf);    // softplus(+conf)
    float bbox = 0.0f, ce = 0.0f, sfm = 0.0f, sfu = 0.0f;
    if (matched) {
        // smooth-L1 vs matched target box
        const float mt0 = tx1[bidx], mt1 = ty1[bidx], mt2 = tx2[bidx], mt3 = ty2[bidx];
        float dd[4] = { px1 - mt0, py1 - mt1, px2 - mt2, py2 - mt3 };
        #pragma unroll
        for (int i = 0; i < 4; ++i) {
            float ad = fabsf(dd[i]);
            bbox += (ad < 1.0f) ? 0.5f * dd[i] * dd[i] : ad - 0.5f;
        }
        // cross-entropy over 79 logits (pred[6:])
        const float* lg = pp + 6;
        float mx = -3.0e38f;
        for (int i = 0; i < NLOGIT; ++i) mx = fmaxf(mx, lg[i]);
        float s = 0.0f;
        for (int i = 0; i < NLOGIT; ++i) s += expf(lg[i] - mx);
        float lse = mx + logf(s);
        int label = (int)tcls[bidx];
        label = label < 0 ? 0 : (label > NLOGIT - 1 ? NLOGIT - 1 : label);
        ce  = lse - lg[label];
        sfm = softplusf(-conf);
    } else {
        sfu = sp_pos;
    }

    // --- block sums (order-fixed, deterministic) ---
    const float mcnt_sum = block_sum(m,      redf);
    const float bbox_sum = block_sum(bbox,   redf);
    const float ce_sum   = block_sum(ce,     redf);
    const float sfm_sum  = block_sum(sfm,    redf);
    const float sfu_sum  = block_sum(sfu,    redf);
    const float sp_sum   = block_sum(sp_pos, redf);

    if (tid == 0) {
        const float mcnt = mcnt_sum;
        const float ucnt = (float)NPRED - mcnt;
        const float bbox_loss = bbox_sum / fmaxf(mcnt * 4.0f, 1.0f);
        const float cls_loss  = ce_sum  / fmaxf(mcnt, 1.0f);
        const float conf_m    = sfm_sum / fmaxf(mcnt, 1.0f);
        const float conf_u    = sfu_sum / fmaxf(ucnt, 1.0f);
        const float conf_loss = (ucnt > 0.0f) ? (conf_m + conf_u) * 0.5f : conf_m;
        const float loss_valid   = bbox_loss + cls_loss + conf_loss;
        const float loss_novalid = sp_sum / (float)NPRED;
        per_sample[b] = (kv_s > 0) ? loss_valid : loss_novalid;
    }
}

__global__ void finalize_kernel(const float* __restrict__ per_sample,
                                float* __restrict__ out, int nb) {
    const int tid = threadIdx.x;
    float v = (tid < nb) ? per_sample[tid] : 0.0f;
    #pragma unroll
    for (int o = 32; o > 0; o >>= 1) v += __shfl_down(v, o);
    __shared__ float r[2];
    if ((tid & 63) == 0) r[tid >> 6] = v;
    __syncthreads();
    if (tid == 0) out[0] = (r[0] + r[1]) / (float)nb;
}

extern "C" void kernel_launch(void* const* d_in, const int* in_sizes, int n_in,
                              void* d_out, int out_size, void* d_ws, size_t ws_size,
                              hipStream_t stream) {
    const float* preds   = (const float*)d_in[0];
    const float* targets = (const float*)d_in[1];
    float* per_sample = (float*)d_ws;
    float* out        = (float*)d_out;

    const int nb = in_sizes[0] / (NPRED * PD);   // = 128

    hipLaunchKernelGGL(detloss_kernel, dim3(nb), dim3(NPRED), 0, stream,
                       preds, targets, per_sample);
    hipLaunchKernelGGL(finalize_kernel, dim3(1), dim3(128), 0, stream,
                       per_sample, out, nb);
}